// Round 12
// baseline (376.640 us; speedup 1.0000x reference)
//
#include <hip/hip_runtime.h>

#define NN 20480
#define NPTS 81920   // B(4) * N(20480)
#define RW 20        // F/L row stride (floats): 16B-aligned, bank-spread
#define PTP 320      // per-point plane stride = 16*RW
#define LOG2E 1.4426950408889634f

// LDS float offsets (both stages): F=0(2560) L=2560(2560) GD=5120(256)
// MID=5376(256,stride32) LGR=5632(8, stage2)  [ACT aliases GD in C1+]
#define LBASE 2560
#define GDB   5120
#define MIDB  5376
#define ACTB  5120
#define LGRB  5632

// transposed/packed weight offsets in ws weight region (floats)
#define P1FCT 0      // [c][o]  34x32, pre-scaled by LOG2E
#define P2FCT 1088
#define P1MWT 2176   // [c][k]  32x16
#define P2MT  2688   // [c][k][h]  32x16x2
#define M2T   3712   // [c][k][j]  32x16x4
#define SCT   5760   // [c][k][j]  16x16x4
#define M3T   6784   // [c][k][j]   4x16x4
#define M4T   7040   // [c][k][j] 128x16x4
#define WTOT  15232

__device__ __forceinline__ float redsum16(float v){
    v += __shfl_xor(v, 1); v += __shfl_xor(v, 2);
    v += __shfl_xor(v, 4); v += __shfl_xor(v, 8);
    return v;
}
__device__ __forceinline__ float redmax16(float v){
    v = fmaxf(v, __shfl_xor(v, 1)); v = fmaxf(v, __shfl_xor(v, 2));
    v = fmaxf(v, __shfl_xor(v, 4)); v = fmaxf(v, __shfl_xor(v, 8));
    return v;
}
__device__ __forceinline__ void wsync(){
    __builtin_amdgcn_wave_barrier();
    __threadfence_block();
    __builtin_amdgcn_wave_barrier();
}
__device__ __forceinline__ float frcp(float x){ return __builtin_amdgcn_rcpf(x); }

// Fast atan2 (minimax deg-9; max err ~1.4e-4 rad; atan2(0,0)=0).
__device__ __forceinline__ float fatan2(float y, float x){
    float ax = fabsf(x), ay = fabsf(y);
    float mx = fmaxf(ax, ay), mn = fminf(ax, ay);
    float z = mn * frcp(mx);
    z = (mx == 0.f) ? 0.f : z;
    float z2 = z * z;
    float a = fmaf(0.05265332f, z2, -0.11643287f);
    a = fmaf(a, z2, 0.19354346f);
    a = fmaf(a, z2, -0.33262347f);
    a = fmaf(a, z2, 0.99997726f);
    a = a * z;
    a = (ay > ax) ? (1.5707963268f - a) : a;
    a = (x < 0.f) ? (3.1415926536f - a) : a;
    return (y < 0.f) ? -a : a;
}

// Batch<->XCD affinity swizzle (grid 10240, XCD = blockIdx%8).
__device__ __forceinline__ int swiz(int bid){
    int x = bid & 7, s = bid >> 3;
    return ((x >> 1) * 2560) + ((x & 1) * 1280) + s;
}

__global__ void k_fill4(float4* out, float val, int n4){
    int i = blockIdx.x * blockDim.x + threadIdx.x;
    int stride = gridDim.x * blockDim.x;
    float4 v = make_float4(val, val, val, val);
    for (; i < n4; i += stride) out[i] = v;
}

// Weight repack: coalesced-for-consumer layouts.
__global__ void k_prep(
    const float* __restrict__ p1fc, const float* __restrict__ p2fc,
    const float* __restrict__ p1mW, const float* __restrict__ p2mW,
    const float* __restrict__ m2W,  const float* __restrict__ scW,
    const float* __restrict__ m3W,  const float* __restrict__ m4W,
    float* __restrict__ wb)
{
    int bid = blockIdx.x;
    if (bid == 0 || bid == 1){           // fc: [o][34] -> [c][32], scaled
        const float* src = bid ? p2fc : p1fc;
        float* dst = wb + (bid ? P2FCT : P1FCT);
        for (int e = threadIdx.x; e < 1088; e += 256){
            int c = e >> 5, o = e & 31;
            dst[e] = src[o*34 + c] * LOG2E;
        }
    } else if (bid == 2){                // p1m: [o=k][32] -> [c][k]
        for (int e = threadIdx.x; e < 512; e += 256){
            int c = e >> 4, k = e & 15;
            wb[P1MWT + e] = p1mW[k*32 + c];
        }
    } else if (bid == 3){                // p2m: -> [c][k][h]
        for (int e = threadIdx.x; e < 1024; e += 256){
            int c = e >> 5, r = e & 31, k = r >> 1, h = r & 1;
            wb[P2MT + e] = p2mW[(k + 16*h)*32 + c];
        }
    } else if (bid == 4){                // m2: -> [c][k][j]
        for (int e = threadIdx.x; e < 2048; e += 256){
            int c = e >> 6, r = e & 63, k = r >> 2, j = r & 3;
            wb[M2T + e] = m2W[(k + 16*j)*32 + c];
        }
    } else if (bid == 5){                // sc: -> [c][k][j]
        for (int e = threadIdx.x; e < 1024; e += 256){
            int c = e >> 6, r = e & 63, k = r >> 2, j = r & 3;
            wb[SCT + e] = scW[(k + 16*j)*16 + c];
        }
    } else if (bid == 6){                // m3: -> [c][k][j]
        for (int e = threadIdx.x; e < 256; e += 256){
            int c = e >> 6, r = e & 63, k = r >> 2, j = r & 3;
            wb[M3T + e] = m3W[(k + 16*j)*4 + c];
        }
    } else if (bid == 7){                // m4: -> [c][k][j]
        for (int e = threadIdx.x; e < 8192; e += 256){
            int c = e >> 6, r = e & 63, k = r >> 2, j = r & 3;
            wb[M4T + e] = m4W[(k + 16*j)*128 + c];
        }
    }
}

__global__ __launch_bounds__(256) void k_feat0(
    const float* __restrict__ featp,
    const float* __restrict__ m1W,
    const float* __restrict__ m1g,
    const float* __restrict__ m1b,
    float* __restrict__ feat0)
{
    int p = blockIdx.x * 256 + threadIdx.x;
    if (p >= NPTS) return;
    int b = p / NN;
    int n = p - b * NN;
    float x[16];
    #pragma unroll
    for (int c = 0; c < 16; c++) x[c] = featp[(b*16 + c)*NN + n];
    float* dst = feat0 + (size_t)p * 16;
    for (int o = 0; o < 16; o++){
        float acc = 0.f;
        #pragma unroll
        for (int c = 0; c < 16; c++) acc = fmaf(m1W[o*16 + c], x[c], acc);
        dst[o] = fmaxf(fmaf(m1g[o], acc, m1b[o]), 0.f);
    }
}

// Phase B: wave = 2 points x 32 channels x 2 passes. Weights pre-scaled by
// LOG2E so softmax uses bare exp2f (v_exp_f32).
__device__ __forceinline__ void phaseB(
    const float* __restrict__ fcT, float* sm, int tid)
{
    const int l  = tid & 63;
    const int o  = l & 31;
    const int h  = l >> 5;
    const int wv = tid >> 6;

    float w[34];
    #pragma unroll
    for (int c = 0; c < 34; c++) w[c] = fcT[c*32 + o];   // coalesced

    #pragma unroll
    for (int pp = 0; pp < 2; pp++){
        const int ptB = (wv << 2) + (pp << 1) + h;
        const float* fPB = sm + ptB*PTP;
        const float* lPB = sm + LBASE + ptB*PTP;
        const float* fsvP = (o < 16) ? (fPB + o) : (lPB + (o - 16));

        float lg[16];
        #pragma unroll
        for (int kk = 0; kk < 16; kk++){
            float2 gd = *(const float2*)&sm[GDB + ptB*32 + kk*2];
            float a = fmaf(w[1], gd.y, w[0]*gd.x);
            const float4* fr = (const float4*)(fPB + kk*RW);
            const float4* lr = (const float4*)(lPB + kk*RW);
            #pragma unroll
            for (int v = 0; v < 4; v++){
                float4 F = fr[v]; float4 L = lr[v];
                a = fmaf(w[2+4*v],  F.x, a); a = fmaf(w[3+4*v],  F.y, a);
                a = fmaf(w[4+4*v],  F.z, a); a = fmaf(w[5+4*v],  F.w, a);
                a = fmaf(w[18+4*v], L.x, a); a = fmaf(w[19+4*v], L.y, a);
                a = fmaf(w[20+4*v], L.z, a); a = fmaf(w[21+4*v], L.w, a);
            }
            lg[kk] = a;
        }
        float m0 = fmaxf(fmaxf(fmaxf(lg[0],lg[1]), fmaxf(lg[2],lg[3])),
                         fmaxf(fmaxf(lg[4],lg[5]), fmaxf(lg[6],lg[7])));
        float m1 = fmaxf(fmaxf(fmaxf(lg[8],lg[9]), fmaxf(lg[10],lg[11])),
                         fmaxf(fmaxf(lg[12],lg[13]), fmaxf(lg[14],lg[15])));
        float mx = fmaxf(m0, m1);
        float s = 0.f, num = 0.f;
        #pragma unroll
        for (int kk = 0; kk < 16; kk++){
            float e = exp2f(lg[kk] - mx);
            s += e;
            num = fmaf(e, fsvP[kk*RW], num);
        }
        sm[MIDB + ptB*32 + o] = num * frcp(s);
    }
}

// ---------------- Stage 1 ----------------  LDS = 5632 floats (22.5 KB)
__global__ __launch_bounds__(128, 2) void k_stage1(
    const float* __restrict__ xyzp,
    const int* __restrict__ nidx,
    const float* __restrict__ feat0,
    const float* __restrict__ lm1W,
    const float* __restrict__ lm1g,
    const float* __restrict__ lm1b,
    const float* __restrict__ wb,
    const float* __restrict__ p1mg,
    const float* __restrict__ p1mb,
    float* __restrict__ feat1)
{
    __shared__ float sm[5632];
    const int k  = threadIdx.x & 15;
    const int pt = threadIdx.x >> 4;
    const int p  = (swiz(blockIdx.x) << 3) + pt;
    const int b  = p / NN;

    // ---- Phase A ----
    {
        const int ii = nidx[(p << 4) + k];
        const int q  = b * NN + ii;
        const float4* an = (const float4*)(feat0 + (size_t)q * 16);
        const float4* as = (const float4*)(feat0 + (size_t)p * 16);
        const float sx = xyzp[p*3 + 0];
        const float sy = xyzp[p*3 + 1];
        const float sz = xyzp[p*3 + 2];
        const float nx = xyzp[q*3 + 0];
        const float ny = xyzp[q*3 + 1];
        const float nz = xyzp[q*3 + 2];

        float* fRow = sm + pt*PTP + k*RW;
        float sd = 0.f;
        #pragma unroll
        for (int v = 0; v < 4; v++){
            float4 A = an[v]; float4 S = as[v];
            ((float4*)fRow)[v] = A;
            sd += fabsf(S.x-A.x) + fabsf(S.y-A.y) + fabsf(S.z-A.z) + fabsf(S.w-A.w);
        }
        float fdis2 = 2.f * __expf(-sd * 0.0625f);   // LAMDA*f_dis

        float rx = sx - nx, ry = sy - ny, rz = sz - nz;
        float r2 = rx*rx + ry*ry;
        float rdis = sqrtf(r2 + rz*rz);
        float ralpha = fatan2(ry, rx);
        float rbeta  = fatan2(rz, sqrtf(r2));
        *(float2*)&sm[GDB + pt*32 + k*2] = make_float2(__expf(-rdis), fdis2);

        float mx = redsum16(nx) * 0.0625f;
        float my = redsum16(ny) * 0.0625f;
        float mz = redsum16(nz) * 0.0625f;
        float dx = sx - mx, dy = sy - my, dz = sz - mz;
        float dalpha = fatan2(dy, dx);
        float dbeta  = fatan2(dz, sqrtf(dx*dx + dy*dy));

        const float r0 = ralpha - dalpha, r1 = rbeta - dbeta;
        float* lRow = sm + LBASE + pt*PTP + k*RW;
        for (int o = 0; o < 16; o++){        // uniform o: s_load weights
            const float* wr = lm1W + o*9;
            float acc =        wr[0]*r0;
            acc = fmaf(wr[1], r1,   acc); acc = fmaf(wr[2], rdis, acc);
            acc = fmaf(wr[3], sx,   acc); acc = fmaf(wr[4], sy,   acc);
            acc = fmaf(wr[5], sz,   acc); acc = fmaf(wr[6], nx,   acc);
            acc = fmaf(wr[7], ny,   acc); acc = fmaf(wr[8], nz,   acc);
            lRow[o] = fmaxf(fmaf(lm1g[o], acc, lm1b[o]), 0.f);
        }
    }
    wsync();

    phaseB(wb + P1FCT, sm, threadIdx.x);
    wsync();

    // ---- Phase C : p1m row k ----
    {
        float mid[32];
        const float4* mp = (const float4*)(sm + MIDB + pt*32);
        #pragma unroll
        for (int i = 0; i < 8; i++){
            float4 t = mp[i];
            mid[4*i]=t.x; mid[4*i+1]=t.y; mid[4*i+2]=t.z; mid[4*i+3]=t.w;
        }
        const float* wt = wb + P1MWT;
        float acc = 0.f;
        #pragma unroll
        for (int c = 0; c < 32; c++) acc = fmaf(wt[c*16 + k], mid[c], acc);
        feat1[(size_t)(p << 4) + k] = fmaxf(fmaf(p1mg[k], acc, p1mb[k]), 0.f);
    }
}

// ---------------- Stage 2 ----------------  LDS = 5640 floats (22.6 KB)
__global__ __launch_bounds__(128, 2) void k_stage2(
    const float* __restrict__ featp,
    const float* __restrict__ xyzp,
    const int* __restrict__ nidx,
    const float* __restrict__ feat1,
    const float* __restrict__ lm1W,
    const float* __restrict__ lm1g,
    const float* __restrict__ lm1b,
    const float* __restrict__ lm2W,
    const float* __restrict__ lm2g,
    const float* __restrict__ lm2b,
    const float* __restrict__ wb,
    const float* __restrict__ p2mg,
    const float* __restrict__ p2mb,
    const float* __restrict__ m2g,
    const float* __restrict__ m2b,
    const float* __restrict__ scg,
    const float* __restrict__ scb,
    const float* __restrict__ m3g,
    const float* __restrict__ m3b,
    const float* __restrict__ m4g,
    const float* __restrict__ m4b,
    float* __restrict__ outp)
{
    __shared__ float sm[5640];
    const int k    = threadIdx.x & 15;
    const int pt   = threadIdx.x >> 4;
    const int pblk = swiz(blockIdx.x);
    const int p    = (pblk << 3) + pt;
    const int b    = p / NN;
    const int n    = p - b * NN;

    const float sx = xyzp[p*3 + 0];
    const float sy = xyzp[p*3 + 1];
    const float sz = xyzp[p*3 + 2];

    // ---- Phase A ----
    {
        const int ii = nidx[(p << 4) + k];
        const int q  = b * NN + ii;
        const float4* an = (const float4*)(feat1 + (size_t)q * 16);
        const float4* as = (const float4*)(feat1 + (size_t)p * 16);
        const float nx = xyzp[q*3 + 0];
        const float ny = xyzp[q*3 + 1];
        const float nz = xyzp[q*3 + 2];

        float* fRow = sm + pt*PTP + k*RW;
        float sd = 0.f;
        #pragma unroll
        for (int v = 0; v < 4; v++){
            float4 A = an[v]; float4 S = as[v];
            ((float4*)fRow)[v] = A;
            sd += fabsf(S.x-A.x) + fabsf(S.y-A.y) + fabsf(S.z-A.z) + fabsf(S.w-A.w);
        }
        float fdis2 = 2.f * __expf(-sd * 0.0625f);

        float rx = sx - nx, ry = sy - ny, rz = sz - nz;
        float r2 = rx*rx + ry*ry;
        float rdis = sqrtf(r2 + rz*rz);
        float ralpha = fatan2(ry, rx);
        float rbeta  = fatan2(rz, sqrtf(r2));
        *(float2*)&sm[GDB + pt*32 + k*2] = make_float2(__expf(-rdis), fdis2);

        float mx = redsum16(nx) * 0.0625f;
        float my = redsum16(ny) * 0.0625f;
        float mz = redsum16(nz) * 0.0625f;
        float dx = sx - mx, dy = sy - my, dz = sz - mz;
        float dalpha = fatan2(dy, dx);
        float dbeta  = fatan2(dz, sqrtf(dx*dx + dy*dy));

        float mxd = redmax16(rdis);
        float nr  = sqrtf(sx*sx + sy*sy + sz*sz);
        if (k == 0) sm[LGRB + pt] = (mxd*mxd*mxd) * frcp(nr*nr*nr);

        const float r0 = ralpha - dalpha, r1 = rbeta - dbeta;
        float rep[9] = { r0, r1, rdis, sx, sy, sz, nx, ny, nz };
        float lrep[16];
        #pragma unroll
        for (int o = 0; o < 16; o++){
            float acc = 0.f;
            #pragma unroll
            for (int c = 0; c < 9; c++) acc = fmaf(lm1W[o*9 + c], rep[c], acc);
            lrep[o] = fmaxf(fmaf(lm1g[o], acc, lm1b[o]), 0.f);
        }
        float* lRow = sm + LBASE + pt*PTP + k*RW;
        for (int o = 0; o < 16; o++){
            float acc = 0.f;
            #pragma unroll
            for (int c = 0; c < 16; c++) acc = fmaf(lm2W[o*16 + c], lrep[c], acc);
            lRow[o] = fmaxf(fmaf(lm2g[o], acc, lm2b[o]), 0.f);   // lrep2
        }
    }
    wsync();

    phaseB(wb + P2FCT, sm, threadIdx.x);
    wsync();

    // ---- Phase C1 : p2m (relu) -> ACT (aliases GD) ----
    {
        float mid[32];
        const float4* mp = (const float4*)(sm + MIDB + pt*32);
        #pragma unroll
        for (int i = 0; i < 8; i++){
            float4 t = mp[i];
            mid[4*i]=t.x; mid[4*i+1]=t.y; mid[4*i+2]=t.z; mid[4*i+3]=t.w;
        }
        const float2* w2 = (const float2*)(wb + P2MT);
        float actA = 0.f, actB = 0.f;
        #pragma unroll
        for (int c = 0; c < 32; c++){
            float2 w = w2[c*16 + k];
            actA = fmaf(w.x, mid[c], actA);
            actB = fmaf(w.y, mid[c], actB);
        }
        sm[ACTB + pt*32 + k]      = fmaxf(fmaf(p2mg[k],    actA, p2mb[k]),    0.f);
        sm[ACTB + pt*32 + k + 16] = fmaxf(fmaf(p2mg[k+16], actB, p2mb[k+16]), 0.f);
    }
    wsync();

    // ---- Phase C2 : m2 + sc + m3 -> sH (aliases pt's F slice) ----
    {
        float act[32];
        const float4* ap = (const float4*)(sm + ACTB + pt*32);
        #pragma unroll
        for (int i = 0; i < 8; i++){
            float4 t = ap[i];
            act[4*i]=t.x; act[4*i+1]=t.y; act[4*i+2]=t.z; act[4*i+3]=t.w;
        }
        const float4* w4m2 = (const float4*)(wb + M2T);
        float hA[4] = {0.f, 0.f, 0.f, 0.f};
        #pragma unroll
        for (int c = 0; c < 32; c++){
            float4 w = w4m2[c*16 + k];
            float a = act[c];
            hA[0] = fmaf(w.x, a, hA[0]); hA[1] = fmaf(w.y, a, hA[1]);
            hA[2] = fmaf(w.z, a, hA[2]); hA[3] = fmaf(w.w, a, hA[3]);
        }
        const float4* w4sc = (const float4*)(wb + SCT);
        float sA4[4] = {0.f, 0.f, 0.f, 0.f};
        #pragma unroll
        for (int c = 0; c < 16; c++){
            float x = featp[(b*16 + c)*NN + n];
            float4 w = w4sc[c*16 + k];
            sA4[0] = fmaf(w.x, x, sA4[0]); sA4[1] = fmaf(w.y, x, sA4[1]);
            sA4[2] = fmaf(w.z, x, sA4[2]); sA4[3] = fmaf(w.w, x, sA4[3]);
        }
        const float lgr = sm[LGRB + pt];
        const float v3[4] = { sx, sy, sz, lgr };
        const float4* w4m3 = (const float4*)(wb + M3T);
        float g4[4] = {0.f, 0.f, 0.f, 0.f};
        #pragma unroll
        for (int c = 0; c < 4; c++){
            float4 w = w4m3[c*16 + k];
            g4[0] = fmaf(w.x, v3[c], g4[0]); g4[1] = fmaf(w.y, v3[c], g4[1]);
            g4[2] = fmaf(w.z, v3[c], g4[2]); g4[3] = fmaf(w.w, v3[c], g4[3]);
        }
        float* sH = sm + pt*PTP;    // F slice (dead after phase B)
        #pragma unroll
        for (int j = 0; j < 4; j++){
            int oo = k + 16*j;
            float scv = fmaf(scg[oo], sA4[j], scb[oo]);
            float m2v = fmaf(m2g[oo], hA[j],  m2b[oo]);
            sH[oo]      = m2v + scv;
            sH[64 + oo] = fmaf(m3g[oo], g4[j], m3b[oo]);
        }
    }
    wsync();

    // ---- Phase C3 : m4 (relu), float4 weight loads ----
    float o4[4] = {0.f, 0.f, 0.f, 0.f};
    {
        const float* hRow = sm + pt*PTP;
        const float4* w44 = (const float4*)(wb + M4T);
        for (int cb = 0; cb < 32; cb++){
            const float4 hv = *(const float4*)(hRow + cb*4);
            float4 wx = w44[(cb*4 + 0)*16 + k];
            float4 wy = w44[(cb*4 + 1)*16 + k];
            float4 wz = w44[(cb*4 + 2)*16 + k];
            float4 ww = w44[(cb*4 + 3)*16 + k];
            o4[0] = fmaf(wx.x, hv.x, o4[0]); o4[1] = fmaf(wx.y, hv.x, o4[1]);
            o4[2] = fmaf(wx.z, hv.x, o4[2]); o4[3] = fmaf(wx.w, hv.x, o4[3]);
            o4[0] = fmaf(wy.x, hv.y, o4[0]); o4[1] = fmaf(wy.y, hv.y, o4[1]);
            o4[2] = fmaf(wy.z, hv.y, o4[2]); o4[3] = fmaf(wy.w, hv.y, o4[3]);
            o4[0] = fmaf(wz.x, hv.z, o4[0]); o4[1] = fmaf(wz.y, hv.z, o4[1]);
            o4[2] = fmaf(wz.z, hv.z, o4[2]); o4[3] = fmaf(wz.w, hv.z, o4[3]);
            o4[0] = fmaf(ww.x, hv.w, o4[0]); o4[1] = fmaf(ww.y, hv.w, o4[1]);
            o4[2] = fmaf(ww.z, hv.w, o4[2]); o4[3] = fmaf(ww.w, hv.w, o4[3]);
        }
    }
    wsync();   // own-wave F region reuse for output staging
    {
        const int w   = threadIdx.x >> 6;     // wave id
        const int l   = threadIdx.x & 63;
        float* sOutW  = sm + w*1280;          // inside own wave's F slices
        const int pt3 = pt & 3;
        #pragma unroll
        for (int j = 0; j < 4; j++)
            sOutW[4*(k + 16*j) + pt3] = fmaxf(fmaf(m4g[k+16*j], o4[j], m4b[k+16*j]), 0.f);
        wsync();
        const int pbase = pblk << 3;
        const int b0 = pbase / NN;
        const int n0 = pbase - b0 * NN + 4*w;
        float4 u = *(const float4*)(sOutW + 4*l);
        *(float4*)(outp + (size_t)(b0*64 + l)*NN + n0) = u;
    }
}

extern "C" void kernel_launch(void* const* d_in, const int* in_sizes, int n_in,
                              void* d_out, int out_size, void* d_ws, size_t ws_size,
                              hipStream_t stream) {
    float* outp = (float*)d_out;

    float fillv = 1.0f;
    bool ok = true;
    if (n_in != 32) { fillv = 5.0f; ok = false; }
    else if (in_sizes[0] != 1310720 || in_sizes[1] != 245760 ||
             in_sizes[31] != 1310720) { fillv = 7.0f; ok = false; }
    else if (out_size != 5242880) { fillv = 9.0f; ok = false; }
    else if (ws_size < ((size_t)NPTS * 16 + WTOT) * sizeof(float)) { fillv = 11.0f; ok = false; }

    k_fill4<<<1024, 256, 0, stream>>>((float4*)outp, fillv, out_size/4);
    if (!ok) return;

    const float* featp = (const float*)d_in[0];
    const float* xyzp  = (const float*)d_in[1];
    const int*   nidx  = (const int*)d_in[31];

    float* feat0 = (float*)d_out;                      // scratch in d_out
    float* feat1 = (float*)d_ws;
    float* wb    = (float*)d_ws + (size_t)NPTS * 16;

    #define W(i) ((const float*)d_in[2 + (i)])
    k_prep<<<8, 256, 0, stream>>>(W(9), W(13), W(10), W(14), W(17), W(20),
                                  W(23), W(26), wb);
    k_feat0<<<NPTS/256, 256, 0, stream>>>(featp, W(0), W(1), W(2), feat0);
    k_stage1<<<NPTS/8, 128, 0, stream>>>(xyzp, nidx, feat0,
        W(3), W(4), W(5), wb, W(11), W(12), feat1);
    k_stage2<<<NPTS/8, 128, 0, stream>>>(featp, xyzp, nidx, feat1,
        W(3), W(4), W(5),          // lm1
        W(6), W(7), W(8),          // lm2
        wb,
        W(15), W(16),              // p2m g/b
        W(18), W(19),              // m2 g/b
        W(21), W(22),              // sc g/b
        W(24), W(25),              // m3 g/b
        W(27), W(28),              // m4 g/b
        outp);
    #undef W
}

// Round 13
// 323.153 us; speedup vs baseline: 1.1655x; 1.1655x over previous
//
#include <hip/hip_runtime.h>

#define NN 20480
#define NPTS 81920   // B(4) * N(20480)
#define MS 36        // MID/ACT row stride (floats)
#define RSH 72       // X row stride in shorts (144 B: 16B-aligned, bank-spread)
#define PTSH 1152    // X shorts per point (16 rows * 72)
#define LOG2E 1.4426950408889634f

// fp32 weight offsets in wb (floats) — round-11 [c][o] flat transposes
#define P1MWT 0      // 512
#define P2MWT 512    // 1024
#define M2WT  1536   // 2048
#define SCWT  3584   // 1024
#define M3WT  4608   // 256
#define M4WT  4864   // 8192
#define BFB   13056  // fp16 B-frags: 2 stages x 2048 shorts
#define WTOT  15104  // floats total

typedef _Float16 half8 __attribute__((ext_vector_type(8)));
typedef float f32x4 __attribute__((ext_vector_type(4)));

__device__ __forceinline__ float redsum16(float v){
    v += __shfl_xor(v, 1); v += __shfl_xor(v, 2);
    v += __shfl_xor(v, 4); v += __shfl_xor(v, 8);
    return v;
}
__device__ __forceinline__ float redmax16(float v){
    v = fmaxf(v, __shfl_xor(v, 1)); v = fmaxf(v, __shfl_xor(v, 2));
    v = fmaxf(v, __shfl_xor(v, 4)); v = fmaxf(v, __shfl_xor(v, 8));
    return v;
}
__device__ __forceinline__ void wsync(){
    __builtin_amdgcn_wave_barrier();
    __threadfence_block();
    __builtin_amdgcn_wave_barrier();
}
__device__ __forceinline__ float frcp(float x){ return __builtin_amdgcn_rcpf(x); }

__device__ __forceinline__ unsigned int ph(float lo, float hi){
    union { _Float16 h[2]; unsigned int u; } cv;
    cv.h[0] = (_Float16)lo; cv.h[1] = (_Float16)hi;
    return cv.u;
}
__device__ __forceinline__ float h2f(short s){
    union { short s; _Float16 h; } cv; cv.s = s;
    return (float)cv.h;
}

// Fast atan2 (minimax deg-9; max err ~1.4e-4 rad; atan2(0,0)=0).
__device__ __forceinline__ float fatan2(float y, float x){
    float ax = fabsf(x), ay = fabsf(y);
    float mx = fmaxf(ax, ay), mn = fminf(ax, ay);
    float z = mn * frcp(mx);
    z = (mx == 0.f) ? 0.f : z;
    float z2 = z * z;
    float a = fmaf(0.05265332f, z2, -0.11643287f);
    a = fmaf(a, z2, 0.19354346f);
    a = fmaf(a, z2, -0.33262347f);
    a = fmaf(a, z2, 0.99997726f);
    a = a * z;
    a = (ay > ax) ? (1.5707963268f - a) : a;
    a = (x < 0.f) ? (3.1415926536f - a) : a;
    return (y < 0.f) ? -a : a;
}

// Batch<->XCD affinity swizzle (grid 10240, XCD = blockIdx%8).
__device__ __forceinline__ int swiz(int bid){
    int x = bid & 7, s = bid >> 3;
    return ((x >> 1) * 2560) + ((x & 1) * 1280) + s;
}

__global__ void k_fill4(float4* out, float val, int n4){
    int i = blockIdx.x * blockDim.x + threadIdx.x;
    int stride = gridDim.x * blockDim.x;
    float4 v = make_float4(val, val, val, val);
    for (; i < n4; i += stride) out[i] = v;
}

// Weight prep: [c][o] fp32 transposes (round-11 layouts) + fp16 MFMA B-frags.
__global__ void k_prep(
    const float* __restrict__ p1fc, const float* __restrict__ p2fc,
    const float* __restrict__ p1mW, const float* __restrict__ p2mW,
    const float* __restrict__ m2W,  const float* __restrict__ scW,
    const float* __restrict__ m3W,  const float* __restrict__ m4W,
    float* __restrict__ wb)
{
    int bid = blockIdx.x;
    if (bid == 0){
        for (int e = threadIdx.x; e < 512; e += 256){
            int c = e >> 4, k = e & 15;
            wb[P1MWT + e] = p1mW[k*32 + c];
        }
    } else if (bid == 1){
        for (int e = threadIdx.x; e < 1024; e += 256){
            int c = e >> 5, o = e & 31;
            wb[P2MWT + e] = p2mW[o*32 + c];
        }
    } else if (bid == 2){
        for (int e = threadIdx.x; e < 2048; e += 256){
            int c = e >> 6, o = e & 63;
            wb[M2WT + e] = m2W[o*32 + c];
        }
    } else if (bid == 3){
        for (int e = threadIdx.x; e < 1024; e += 256){
            int c = e >> 6, o = e & 63;
            wb[SCWT + e] = scW[o*16 + c];
        }
    } else if (bid == 4){
        for (int e = threadIdx.x; e < 256; e += 256){
            int c = e >> 6, o = e & 63;
            wb[M3WT + e] = m3W[o*4 + c];
        }
    } else if (bid == 5){
        for (int e = threadIdx.x; e < 8192; e += 256){
            int c = e >> 6, o = e & 63;
            wb[M4WT + e] = m4W[o*128 + c];
        }
    } else if (bid == 6 || bid == 7){
        // fc B-frags: value = fc[o][c]*LOG2E as fp16, laid out so lane l of
        // phase B loads frag (t,q) at [((t*2+q)*64+l)*8 + j], with
        // kk=(l>>4)*8+j, c=q*32+kk, o=(l&15)+16t.  (B[k][n]: n=lane&15,
        // k=quad*8+j — standard gfx950 16x16x32 B layout.)
        const float* src = (bid == 6) ? p1fc : p2fc;
        short* dst = (short*)(wb + BFB) + (bid - 6) * 2048;
        for (int e = threadIdx.x; e < 2048; e += 256){
            int j = e & 7, l = (e >> 3) & 63, tq = (e >> 9) & 3;
            int q = tq & 1, t = tq >> 1;
            int kk = ((l >> 4) << 3) + j;
            int c = q*32 + kk;
            int o = (l & 15) + 16*t;
            float v = (c < 34) ? src[o*34 + c] * LOG2E : 0.f;
            union { _Float16 h; short s; } cv; cv.h = (_Float16)v;
            dst[e] = cv.s;
        }
    }
}

__global__ __launch_bounds__(256) void k_feat0(
    const float* __restrict__ featp,
    const float* __restrict__ m1W,
    const float* __restrict__ m1g,
    const float* __restrict__ m1b,
    float* __restrict__ feat0)
{
    int p = blockIdx.x * 256 + threadIdx.x;
    if (p >= NPTS) return;
    int b = p / NN;
    int n = p - b * NN;
    float x[16];
    #pragma unroll
    for (int c = 0; c < 16; c++) x[c] = featp[(b*16 + c)*NN + n];
    float* dst = feat0 + (size_t)p * 16;
    for (int o = 0; o < 16; o++){
        float acc = 0.f;
        #pragma unroll
        for (int c = 0; c < 16; c++) acc = fmaf(m1W[o*16 + c], x[c], acc);
        dst[o] = fmaxf(fmaf(m1g[o], acc, m1b[o]), 0.f);
    }
}

// Pool one o-tile: softmax over k (rows; 4 in-lane + 2 butterflies) and
// attention-weighted sum of X[c][k].
__device__ __forceinline__ float poolT(f32x4 a, const short* base, int c, int g){
    float m = fmaxf(fmaxf(a[0], a[1]), fmaxf(a[2], a[3]));
    m = fmaxf(m, __shfl_xor(m, 16)); m = fmaxf(m, __shfl_xor(m, 32));
    float e0 = exp2f(a[0] - m), e1 = exp2f(a[1] - m);
    float e2 = exp2f(a[2] - m), e3 = exp2f(a[3] - m);
    float s = (e0 + e1) + (e2 + e3);
    const short* xc = base + c;
    float x0 = h2f(xc[(g*4 + 0)*RSH]), x1 = h2f(xc[(g*4 + 1)*RSH]);
    float x2 = h2f(xc[(g*4 + 2)*RSH]), x3 = h2f(xc[(g*4 + 3)*RSH]);
    float num = fmaf(e3, x3, fmaf(e2, x2, fmaf(e1, x1, e0*x0)));
    s   += __shfl_xor(s, 16);   s   += __shfl_xor(s, 32);
    num += __shfl_xor(num, 16); num += __shfl_xor(num, 32);
    return num * frcp(s);
}

// Phase B via MFMA: per point D[k][o-tile] = X^T · W^T (K=64, c 34..63 zero).
__device__ __forceinline__ void phaseB_mfma(
    const short* xs, const short* bfS, float* smMid, int tid)
{
    const half8* bf = (const half8*)bfS;
    const int l = tid & 63, wv = tid >> 6;
    const int o = l & 15, g = l >> 4;
    half8 B00 = bf[l], B01 = bf[64 + l], B10 = bf[128 + l], B11 = bf[192 + l];
    #pragma unroll
    for (int pp = 0; pp < 4; pp++){
        const int pt = wv*4 + pp;
        const short* base = xs + pt*PTSH;
        const half8* ap = (const half8*)(base + (l & 15)*RSH + g*8);
        half8 A0 = ap[0];        // c = g*8+j
        half8 A1 = ap[4];        // c = 32 + g*8+j
        f32x4 z = {0.f, 0.f, 0.f, 0.f};
        f32x4 a0 = __builtin_amdgcn_mfma_f32_16x16x32_f16(A0, B00, z, 0, 0, 0);
        a0       = __builtin_amdgcn_mfma_f32_16x16x32_f16(A1, B01, a0, 0, 0, 0);
        f32x4 a1 = __builtin_amdgcn_mfma_f32_16x16x32_f16(A0, B10, z, 0, 0, 0);
        a1       = __builtin_amdgcn_mfma_f32_16x16x32_f16(A1, B11, a1, 0, 0, 0);
        float mid0 = poolT(a0, base, 2 + o,      g);
        float mid1 = poolT(a1, base, 2 + o + 16, g);
        if (g == 0){
            smMid[pt*MS + o]      = mid0;
            smMid[pt*MS + o + 16] = mid1;
        }
    }
}

// ---------------- Stage 1 ----------------
// LDS floats: X(half rows)=0..4608, MID=4608..4896
__global__ __launch_bounds__(128, 2) void k_stage1(
    const float* __restrict__ xyzp,
    const int* __restrict__ nidx,
    const float* __restrict__ feat0,
    const float* __restrict__ lm1W,
    const float* __restrict__ lm1g,
    const float* __restrict__ lm1b,
    const float* __restrict__ wb,
    const float* __restrict__ p1mg,
    const float* __restrict__ p1mb,
    float* __restrict__ feat1)
{
    __shared__ float sm[4896];
    short* xs = (short*)sm;
    const int k  = threadIdx.x & 15;
    const int pt = threadIdx.x >> 4;
    const int p  = (swiz(blockIdx.x) << 3) + pt;
    const int b  = p / NN;

    // ---- Phase A: geometry + lm1 + gather -> packed fp16 X rows ----
    {
        const int ii = nidx[(p << 4) + k];
        const int q  = b * NN + ii;
        const float4* an = (const float4*)(feat0 + (size_t)q * 16);
        const float4* as = (const float4*)(feat0 + (size_t)p * 16);
        const float sx = xyzp[p*3 + 0];
        const float sy = xyzp[p*3 + 1];
        const float sz = xyzp[p*3 + 2];
        const float nx = xyzp[q*3 + 0];
        const float ny = xyzp[q*3 + 1];
        const float nz = xyzp[q*3 + 2];

        float4 A0 = an[0], A1 = an[1], A2 = an[2], A3 = an[3];
        float sd = 0.f;
        {
            float4 S0 = as[0], S1 = as[1], S2 = as[2], S3 = as[3];
            sd += fabsf(S0.x-A0.x) + fabsf(S0.y-A0.y) + fabsf(S0.z-A0.z) + fabsf(S0.w-A0.w);
            sd += fabsf(S1.x-A1.x) + fabsf(S1.y-A1.y) + fabsf(S1.z-A1.z) + fabsf(S1.w-A1.w);
            sd += fabsf(S2.x-A2.x) + fabsf(S2.y-A2.y) + fabsf(S2.z-A2.z) + fabsf(S2.w-A2.w);
            sd += fabsf(S3.x-A3.x) + fabsf(S3.y-A3.y) + fabsf(S3.z-A3.z) + fabsf(S3.w-A3.w);
        }
        float fdis2 = 2.f * __expf(-sd * 0.0625f);   // LAMDA*f_dis

        float rx = sx - nx, ry = sy - ny, rz = sz - nz;
        float r2 = rx*rx + ry*ry;
        float rdis = sqrtf(r2 + rz*rz);
        float ralpha = fatan2(ry, rx);
        float rbeta  = fatan2(rz, sqrtf(r2));
        float gdis = __expf(-rdis);

        float mx = redsum16(nx) * 0.0625f;
        float my = redsum16(ny) * 0.0625f;
        float mz = redsum16(nz) * 0.0625f;
        float dx = sx - mx, dy = sy - my, dz = sz - mz;
        float dalpha = fatan2(dy, dx);
        float dbeta  = fatan2(dz, sqrtf(dx*dx + dy*dy));

        float rep[9] = { ralpha - dalpha, rbeta - dbeta, rdis, sx, sy, sz, nx, ny, nz };
        float lrep[16];
        #pragma unroll
        for (int o = 0; o < 16; o++){
            float acc = 0.f;
            #pragma unroll
            for (int c = 0; c < 9; c++) acc = fmaf(lm1W[o*9 + c], rep[c], acc);
            lrep[o] = fmaxf(fmaf(lm1g[o], acc, lm1b[o]), 0.f);
        }

        uint4* rp = (uint4*)(xs + pt*PTSH + k*RSH);
        uint4 U;
        U.x = ph(gdis, fdis2); U.y = ph(A0.x, A0.y);
        U.z = ph(A0.z, A0.w);  U.w = ph(A1.x, A1.y);
        rp[0] = U;
        U.x = ph(A1.z, A1.w);  U.y = ph(A2.x, A2.y);
        U.z = ph(A2.z, A2.w);  U.w = ph(A3.x, A3.y);
        rp[1] = U;
        U.x = ph(A3.z, A3.w);      U.y = ph(lrep[0], lrep[1]);
        U.z = ph(lrep[2], lrep[3]); U.w = ph(lrep[4], lrep[5]);
        rp[2] = U;
        U.x = ph(lrep[6], lrep[7]);   U.y = ph(lrep[8], lrep[9]);
        U.z = ph(lrep[10], lrep[11]); U.w = ph(lrep[12], lrep[13]);
        rp[3] = U;
        U.x = ph(lrep[14], lrep[15]); U.y = 0u; U.z = 0u; U.w = 0u;
        rp[4] = U;
        uint4 Z = {0u, 0u, 0u, 0u};
        rp[5] = Z; rp[6] = Z; rp[7] = Z;
    }
    wsync();

    phaseB_mfma(xs, (const short*)(wb + BFB), sm + 4608, threadIdx.x);
    wsync();

    // ---- Phase C: p1m row k ----
    {
        float mid[32];
        const float4* mp = (const float4*)(sm + 4608 + pt*MS);
        #pragma unroll
        for (int i = 0; i < 8; i++){
            float4 t = mp[i];
            mid[4*i]=t.x; mid[4*i+1]=t.y; mid[4*i+2]=t.z; mid[4*i+3]=t.w;
        }
        const float* wt = wb + P1MWT;
        float acc = 0.f;
        #pragma unroll
        for (int c = 0; c < 32; c++) acc = fmaf(wt[c*16 + k], mid[c], acc);
        feat1[(size_t)(p << 4) + k] = fmaxf(fmaf(p1mg[k], acc, p1mb[k]), 0.f);
    }
}

// ---------------- Stage 2 ----------------
// LDS floats: X=0..4608, MID/ACT=4608..4896 (aliased), LGR=4896..4904
// sH aliases pt's X slice (576 floats); sOut at wave base +288.
__global__ __launch_bounds__(128, 2) void k_stage2(
    const float* __restrict__ featp,
    const float* __restrict__ xyzp,
    const int* __restrict__ nidx,
    const float* __restrict__ feat1,
    const float* __restrict__ lm1W,
    const float* __restrict__ lm1g,
    const float* __restrict__ lm1b,
    const float* __restrict__ lm2W,
    const float* __restrict__ lm2g,
    const float* __restrict__ lm2b,
    const float* __restrict__ wb,
    const float* __restrict__ p2mg,
    const float* __restrict__ p2mb,
    const float* __restrict__ m2g,
    const float* __restrict__ m2b,
    const float* __restrict__ scg,
    const float* __restrict__ scb,
    const float* __restrict__ m3g,
    const float* __restrict__ m3b,
    const float* __restrict__ m4g,
    const float* __restrict__ m4b,
    float* __restrict__ outp)
{
    __shared__ float sm[4904];
    short* xs = (short*)sm;
    const int k    = threadIdx.x & 15;
    const int pt   = threadIdx.x >> 4;
    const int pblk = swiz(blockIdx.x);
    const int p    = (pblk << 3) + pt;
    const int b    = p / NN;
    const int n    = p - b * NN;

    // ---- Phase A ----
    {
        const int ii = nidx[(p << 4) + k];
        const int q  = b * NN + ii;
        const float4* an = (const float4*)(feat1 + (size_t)q * 16);
        const float4* as = (const float4*)(feat1 + (size_t)p * 16);
        const float sx = xyzp[p*3 + 0];
        const float sy = xyzp[p*3 + 1];
        const float sz = xyzp[p*3 + 2];
        const float nx = xyzp[q*3 + 0];
        const float ny = xyzp[q*3 + 1];
        const float nz = xyzp[q*3 + 2];

        float4 A0 = an[0], A1 = an[1], A2 = an[2], A3 = an[3];
        float sd = 0.f;
        {
            float4 S0 = as[0], S1 = as[1], S2 = as[2], S3 = as[3];
            sd += fabsf(S0.x-A0.x) + fabsf(S0.y-A0.y) + fabsf(S0.z-A0.z) + fabsf(S0.w-A0.w);
            sd += fabsf(S1.x-A1.x) + fabsf(S1.y-A1.y) + fabsf(S1.z-A1.z) + fabsf(S1.w-A1.w);
            sd += fabsf(S2.x-A2.x) + fabsf(S2.y-A2.y) + fabsf(S2.z-A2.z) + fabsf(S2.w-A2.w);
            sd += fabsf(S3.x-A3.x) + fabsf(S3.y-A3.y) + fabsf(S3.z-A3.z) + fabsf(S3.w-A3.w);
        }
        float fdis2 = 2.f * __expf(-sd * 0.0625f);

        float rx = sx - nx, ry = sy - ny, rz = sz - nz;
        float r2 = rx*rx + ry*ry;
        float rdis = sqrtf(r2 + rz*rz);
        float ralpha = fatan2(ry, rx);
        float rbeta  = fatan2(rz, sqrtf(r2));
        float gdis = __expf(-rdis);

        float mx = redsum16(nx) * 0.0625f;
        float my = redsum16(ny) * 0.0625f;
        float mz = redsum16(nz) * 0.0625f;
        float dx = sx - mx, dy = sy - my, dz = sz - mz;
        float dalpha = fatan2(dy, dx);
        float dbeta  = fatan2(dz, sqrtf(dx*dx + dy*dy));

        float mxd = redmax16(rdis);
        float nr  = sqrtf(sx*sx + sy*sy + sz*sz);
        if (k == 0) sm[4896 + pt] = (mxd*mxd*mxd) * frcp(nr*nr*nr);

        float rep[9] = { ralpha - dalpha, rbeta - dbeta, rdis, sx, sy, sz, nx, ny, nz };
        float lrep[16];
        #pragma unroll
        for (int o = 0; o < 16; o++){
            float acc = 0.f;
            #pragma unroll
            for (int c = 0; c < 9; c++) acc = fmaf(lm1W[o*9 + c], rep[c], acc);
            lrep[o] = fmaxf(fmaf(lm1g[o], acc, lm1b[o]), 0.f);
        }
        float lrep2[16];
        #pragma unroll
        for (int o = 0; o < 16; o++){
            float acc = 0.f;
            #pragma unroll
            for (int c = 0; c < 16; c++) acc = fmaf(lm2W[o*16 + c], lrep[c], acc);
            lrep2[o] = fmaxf(fmaf(lm2g[o], acc, lm2b[o]), 0.f);
        }

        uint4* rp = (uint4*)(xs + pt*PTSH + k*RSH);
        uint4 U;
        U.x = ph(gdis, fdis2); U.y = ph(A0.x, A0.y);
        U.z = ph(A0.z, A0.w);  U.w = ph(A1.x, A1.y);
        rp[0] = U;
        U.x = ph(A1.z, A1.w);  U.y = ph(A2.x, A2.y);
        U.z = ph(A2.z, A2.w);  U.w = ph(A3.x, A3.y);
        rp[1] = U;
        U.x = ph(A3.z, A3.w);        U.y = ph(lrep2[0], lrep2[1]);
        U.z = ph(lrep2[2], lrep2[3]); U.w = ph(lrep2[4], lrep2[5]);
        rp[2] = U;
        U.x = ph(lrep2[6], lrep2[7]);   U.y = ph(lrep2[8], lrep2[9]);
        U.z = ph(lrep2[10], lrep2[11]); U.w = ph(lrep2[12], lrep2[13]);
        rp[3] = U;
        U.x = ph(lrep2[14], lrep2[15]); U.y = 0u; U.z = 0u; U.w = 0u;
        rp[4] = U;
        uint4 Z = {0u, 0u, 0u, 0u};
        rp[5] = Z; rp[6] = Z; rp[7] = Z;
    }
    wsync();

    phaseB_mfma(xs, (const short*)(wb + BFB) + 2048, sm + 4608, threadIdx.x);
    wsync();

    // ---- Phase C1: p2m (relu); ACT aliases MID (read-all then overwrite) ----
    {
        float mid[32];
        const float4* mp = (const float4*)(sm + 4608 + pt*MS);
        #pragma unroll
        for (int i = 0; i < 8; i++){
            float4 t = mp[i];
            mid[4*i]=t.x; mid[4*i+1]=t.y; mid[4*i+2]=t.z; mid[4*i+3]=t.w;
        }
        wsync();   // all MID reads complete before ACT overwrites
        const float* wt = wb + P2MWT;
        float actA = 0.f, actB = 0.f;
        #pragma unroll
        for (int c = 0; c < 32; c++){
            actA = fmaf(wt[c*32 + k],      mid[c], actA);
            actB = fmaf(wt[c*32 + k + 16], mid[c], actB);
        }
        sm[4608 + pt*MS + k]      = fmaxf(fmaf(p2mg[k],    actA, p2mb[k]),    0.f);
        sm[4608 + pt*MS + k + 16] = fmaxf(fmaf(p2mg[k+16], actB, p2mb[k+16]), 0.f);
    }
    wsync();

    // ---- Phase C2: m2 + sc + m3 -> sH (aliases pt's X slice) ----
    {
        float act[32];
        const float4* ap = (const float4*)(sm + 4608 + pt*MS);
        #pragma unroll
        for (int i = 0; i < 8; i++){
            float4 t = ap[i];
            act[4*i]=t.x; act[4*i+1]=t.y; act[4*i+2]=t.z; act[4*i+3]=t.w;
        }
        const float* wt2 = wb + M2WT;
        float hA[4] = {0.f, 0.f, 0.f, 0.f};
        #pragma unroll
        for (int c = 0; c < 32; c++){
            float a = act[c];
            #pragma unroll
            for (int j = 0; j < 4; j++)
                hA[j] = fmaf(wt2[c*64 + k + 16*j], a, hA[j]);
        }
        const float* wts = wb + SCWT;
        float sA4[4] = {0.f, 0.f, 0.f, 0.f};
        for (int i = 0; i < 4; i++){
            float x0 = featp[(b*16 + 4*i + 0)*NN + n];
            float x1 = featp[(b*16 + 4*i + 1)*NN + n];
            float x2 = featp[(b*16 + 4*i + 2)*NN + n];
            float x3 = featp[(b*16 + 4*i + 3)*NN + n];
            #pragma unroll
            for (int j = 0; j < 4; j++){
                sA4[j] = fmaf(wts[(4*i+0)*64 + k + 16*j], x0, sA4[j]);
                sA4[j] = fmaf(wts[(4*i+1)*64 + k + 16*j], x1, sA4[j]);
                sA4[j] = fmaf(wts[(4*i+2)*64 + k + 16*j], x2, sA4[j]);
                sA4[j] = fmaf(wts[(4*i+3)*64 + k + 16*j], x3, sA4[j]);
            }
        }
        const float sx = xyzp[p*3 + 0];
        const float sy = xyzp[p*3 + 1];
        const float sz = xyzp[p*3 + 2];
        const float lgr = sm[4896 + pt];
        const float v3[4] = { sx, sy, sz, lgr };
        const float* wt3 = wb + M3WT;
        float* sH = sm + pt*576;
        #pragma unroll
        for (int j = 0; j < 4; j++){
            int oo = k + 16*j;
            float scv = fmaf(scg[oo], sA4[j], scb[oo]);
            float m2v = fmaf(m2g[oo], hA[j],  m2b[oo]);
            float acc = 0.f;
            #pragma unroll
            for (int c = 0; c < 4; c++) acc = fmaf(wt3[c*64 + oo], v3[c], acc);
            sH[oo]      = m2v + scv;
            sH[64 + oo] = fmaf(m3g[oo], acc, m3b[oo]);
        }
    }
    wsync();

    // ---- Phase C3: m4 (relu) ----
    float o4[4] = {0.f, 0.f, 0.f, 0.f};
    {
        const float* hRow = sm + pt*576;
        const float* wt4 = wb + M4WT;
        for (int cb = 0; cb < 32; cb++){
            const float4 hv = *(const float4*)(hRow + cb*4);
            const float* w0 = wt4 + (cb*4)*64 + k;
            #pragma unroll
            for (int j = 0; j < 4; j++){
                o4[j] = fmaf(w0[16*j],       hv.x, o4[j]);
                o4[j] = fmaf(w0[64 + 16*j],  hv.y, o4[j]);
                o4[j] = fmaf(w0[128 + 16*j], hv.z, o4[j]);
                o4[j] = fmaf(w0[192 + 16*j], hv.w, o4[j]);
            }
        }
    }
    wsync();
    {
        const int w   = threadIdx.x >> 6;
        const int l   = threadIdx.x & 63;
        float* sOutW  = sm + w*2304 + 288;   // inside own wave's X region
        const int pt3 = pt & 3;
        #pragma unroll
        for (int j = 0; j < 4; j++)
            sOutW[4*(k + 16*j) + pt3] = fmaxf(fmaf(m4g[k+16*j], o4[j], m4b[k+16*j]), 0.f);
        wsync();
        const int pbase = pblk << 3;
        const int b0 = pbase / NN;
        const int n0 = pbase - b0 * NN + 4*w;
        float4 u = *(const float4*)(sOutW + 4*l);
        *(float4*)(outp + (size_t)(b0*64 + l)*NN + n0) = u;
    }
}

extern "C" void kernel_launch(void* const* d_in, const int* in_sizes, int n_in,
                              void* d_out, int out_size, void* d_ws, size_t ws_size,
                              hipStream_t stream) {
    float* outp = (float*)d_out;

    float fillv = 1.0f;
    bool ok = true;
    if (n_in != 32) { fillv = 5.0f; ok = false; }
    else if (in_sizes[0] != 1310720 || in_sizes[1] != 245760 ||
             in_sizes[31] != 1310720) { fillv = 7.0f; ok = false; }
    else if (out_size != 5242880) { fillv = 9.0f; ok = false; }
    else if (ws_size < ((size_t)NPTS * 16 + WTOT) * sizeof(float)) { fillv = 11.0f; ok = false; }

    k_fill4<<<1024, 256, 0, stream>>>((float4*)outp, fillv, out_size/4);
    if (!ok) return;

    const float* featp = (const float*)d_in[0];
    const float* xyzp  = (const float*)d_in[1];
    const int*   nidx  = (const int*)d_in[31];

    float* feat0 = (float*)d_out;                      // scratch in d_out
    float* feat1 = (float*)d_ws;
    float* wb    = (float*)d_ws + (size_t)NPTS * 16;

    #define W(i) ((const float*)d_in[2 + (i)])
    k_prep<<<8, 256, 0, stream>>>(W(9), W(13), W(10), W(14), W(17), W(20),
                                  W(23), W(26), wb);
    k_feat0<<<NPTS/256, 256, 0, stream>>>(featp, W(0), W(1), W(2), feat0);
    k_stage1<<<NPTS/8, 128, 0, stream>>>(xyzp, nidx, feat0,
        W(3), W(4), W(5), wb, W(11), W(12), feat1);
    k_stage2<<<NPTS/8, 128, 0, stream>>>(featp, xyzp, nidx, feat1,
        W(3), W(4), W(5),          // lm1
        W(6), W(7), W(8),          // lm2
        wb,
        W(15), W(16),              // p2m g/b
        W(18), W(19),              // m2 g/b
        W(21), W(22),              // sc g/b
        W(24), W(25),              // m3 g/b
        W(27), W(28),              // m4 g/b
        outp);
    #undef W
}